// Round 1
// 334.711 us; speedup vs baseline: 1.0148x; 1.0148x over previous
//
#include <hip/hip_runtime.h>

#define N_NODES 50000
#define N_EDGES 800000
#define FEAT    256

typedef __bf16 v8bf __attribute__((ext_vector_type(8)));
typedef float  v4f  __attribute__((ext_vector_type(4)));

__device__ __forceinline__ float bf2f(ushort u) {
    return __uint_as_float(((unsigned int)u) << 16);
}
__device__ __forceinline__ ushort f2bf(float f) {
    unsigned int u = __float_as_uint(f);
    u += 0x7FFFu + ((u >> 16) & 1u);   // RNE
    return (ushort)(u >> 16);
}

// ---------------- dtype detector ----------------
// bf16 w: all |w| <= 0.1531 (glorot limit) -> count 0.
// fp32 w read as bf16 ushorts: low halves have uniform exponent bits -> ~16k count.
__global__ void k_detect(const ushort* __restrict__ W, int* __restrict__ flag) {
    int t = threadIdx.x;
    int cnt = 0;
    for (int i = 0; i < 256; ++i) {
        float v = bf2f(W[t * 256 + i]);
        if (fabsf(v) > 0.2f) cnt++;
    }
    if (cnt) atomicAdd(flag, cnt);
}

// ---------------- w transpose: wT[n][k] = w[k][n], canonical bf16 out ----------------
__global__ void k_transpose(const void* __restrict__ Wv, ushort* __restrict__ WT,
                            const int* __restrict__ flag) {
    bool isf32 = (*flag > 1000);
    int n = blockIdx.x;          // 0..255
    int k = threadIdx.x;         // 0..255
    ushort v;
    if (isf32) v = f2bf(((const float*)Wv)[k * 256 + n]);
    else       v = ((const ushort*)Wv)[k * 256 + n];
    WT[n * 256 + k] = v;
}

// ---------------- histogram of rows ----------------
__global__ void k_hist(const int* __restrict__ rows, int* __restrict__ counts) {
    int e = blockIdx.x * 256 + threadIdx.x;
    if (e < N_EDGES) atomicAdd(&counts[rows[e]], 1);
}

// ---------------- scan kernels (exclusive prefix over counts) ----------------
__global__ void k_scan1(const int* __restrict__ counts, int* __restrict__ incl,
                        int* __restrict__ bsums, int n) {
    int t = threadIdx.x;
    int i = blockIdx.x * 256 + t;
    int v = (i < n) ? counts[i] : 0;
    int lane = t & 63, wv = t >> 6;
    __shared__ int wsum[4];
    int s = v;
    #pragma unroll
    for (int d = 1; d < 64; d <<= 1) {
        int tt = __shfl_up(s, d, 64);
        if (lane >= d) s += tt;
    }
    if (lane == 63) wsum[wv] = s;
    __syncthreads();
    int add = 0;
    #pragma unroll
    for (int k = 0; k < 4; k++) if (k < wv) add += wsum[k];
    s += add;
    if (i < n) incl[i] = s;
    if (t == 255) bsums[blockIdx.x] = s;   // block total
}

__global__ void k_scan2(int* __restrict__ bsums, int nb) {
    int t = threadIdx.x;
    int v = (t < nb) ? bsums[t] : 0;
    int lane = t & 63, wv = t >> 6;
    __shared__ int wsum[4];
    int s = v;
    #pragma unroll
    for (int d = 1; d < 64; d <<= 1) {
        int tt = __shfl_up(s, d, 64);
        if (lane >= d) s += tt;
    }
    if (lane == 63) wsum[wv] = s;
    __syncthreads();
    int add = 0;
    #pragma unroll
    for (int k = 0; k < 4; k++) if (k < wv) add += wsum[k];
    s += add;
    if (t < nb) bsums[t] = s - v;          // exclusive
}

__global__ void k_scan3(int* __restrict__ row_ptr, const int* __restrict__ counts,
                        const int* __restrict__ boff, int n) {
    int i = blockIdx.x * 256 + threadIdx.x;
    if (i < n) row_ptr[i] = row_ptr[i] + boff[blockIdx.x] - counts[i];  // incl -> excl
}

// ---------------- scatter edges into CSR order (split cols / bf16 vals) ----------------
__global__ void k_scatter(const int* __restrict__ rows, const int* __restrict__ cols,
                          const void* __restrict__ valsv, const int* __restrict__ row_ptr,
                          int* __restrict__ cursor, int* __restrict__ ecols,
                          ushort* __restrict__ evals, const int* __restrict__ flag) {
    bool isf32 = (*flag > 1000);
    int e = blockIdx.x * 256 + threadIdx.x;
    if (e < N_EDGES) {
        int r = rows[e];
        int p = row_ptr[r] + atomicAdd(&cursor[r], 1);
        ushort v;
        if (isf32) v = f2bf(((const float*)valsv)[e]);
        else       v = ((const ushort*)valsv)[e];
        ecols[p] = cols[e];
        evals[p] = v;
    }
}

// ---------------- SpMM: T = Adj * X, one wave per row, T -> d_out ----------------
// Batched-8 inner loop: load 8 (col,val) pairs (1-2 cache lines), then issue 8
// independent row-gathers back-to-back -> ~2 memory round-trips per batch instead
// of ~1 per 2 edges. Tail edges are clamped to the last real edge with val=0
// (clamped gathers hit L1 -> no extra L2-miss traffic).
__global__ __launch_bounds__(256) void k_spmm(const void* __restrict__ Xv,
                                              const int* __restrict__ ecols,
                                              const ushort* __restrict__ evals,
                                              const int* __restrict__ rptr,
                                              const int* __restrict__ counts,
                                              const int* __restrict__ flag,
                                              void* __restrict__ T) {
    bool isf32 = (*flag > 1000);
    int wv = threadIdx.x >> 6, lane = threadIdx.x & 63;
    int r = blockIdx.x * 4 + wv;               // 12500 * 4 = 50000 exactly
    int start = rptr[r];
    int cnt   = counts[r];
    int f = lane * 4;
    float a0 = 0.f, a1 = 0.f, a2 = 0.f, a3 = 0.f;
    int nbatch = (cnt + 7) >> 3;
    if (isf32) {
        const float* Xf = (const float*)Xv;
        for (int b = 0; b < nbatch; ++b) {
            int j0 = b * 8;
            int cc[8]; float vv[8];
            #pragma unroll
            for (int i = 0; i < 8; ++i) {
                int jj = j0 + i;
                int e  = start + (jj < cnt ? jj : cnt - 1);
                cc[i] = ecols[e];
                vv[i] = (jj < cnt) ? bf2f(evals[e]) : 0.f;
            }
            float4 g[8];
            #pragma unroll
            for (int i = 0; i < 8; ++i)
                g[i] = *(const float4*)(Xf + (size_t)cc[i] * 256 + f);
            #pragma unroll
            for (int i = 0; i < 8; ++i) {
                float v = vv[i];
                a0 = fmaf(v, g[i].x, a0); a1 = fmaf(v, g[i].y, a1);
                a2 = fmaf(v, g[i].z, a2); a3 = fmaf(v, g[i].w, a3);
            }
        }
    } else {
        const ushort* Xb = (const ushort*)Xv;
        for (int b = 0; b < nbatch; ++b) {
            int j0 = b * 8;
            int cc[8]; float vv[8];
            #pragma unroll
            for (int i = 0; i < 8; ++i) {
                int jj = j0 + i;
                int e  = start + (jj < cnt ? jj : cnt - 1);
                cc[i] = ecols[e];
                vv[i] = (jj < cnt) ? bf2f(evals[e]) : 0.f;
            }
            ushort4 g[8];
            #pragma unroll
            for (int i = 0; i < 8; ++i)
                g[i] = *(const ushort4*)(Xb + (size_t)cc[i] * 256 + f);
            #pragma unroll
            for (int i = 0; i < 8; ++i) {
                float v = vv[i];
                a0 = fmaf(v, bf2f(g[i].x), a0); a1 = fmaf(v, bf2f(g[i].y), a1);
                a2 = fmaf(v, bf2f(g[i].z), a2); a3 = fmaf(v, bf2f(g[i].w), a3);
            }
        }
    }
    // NO relu here — T is the pre-projection aggregate
    if (isf32) {
        float* Tf = (float*)T;
        float4 o = make_float4(a0, a1, a2, a3);
        *(float4*)(Tf + (size_t)r * 256 + f) = o;
    } else {
        ushort* Tb = (ushort*)T;
        ushort4 o;
        o.x = f2bf(a0); o.y = f2bf(a1); o.z = f2bf(a2); o.w = f2bf(a3);
        *(ushort4*)(Tb + (size_t)r * 256 + f) = o;
    }
}

// ---------------- in-place GEMM: out = relu(T * W), T lives in d_out ----------------
// block = 256 thr (4 waves); each block owns 64 rows.
// Restructured: n-tile loop moved INSIDE the k-loop. Per k-step we stage the full
// 256-row B chunk (16 KB) once and do 16 MFMAs per wave between one barrier pair
// -> 16 barriers/block instead of 64. A (64x256) fully staged in LDS BEFORE any
// write-back -> in-place is safe.
#define ASTRIDE 264
#define BSTRIDE 40
__global__ __launch_bounds__(256) void k_gemm(void* __restrict__ Tv,
                                              const ushort* __restrict__ WT,
                                              const int* __restrict__ flag) {
    bool isf32 = (*flag > 1000);
    __shared__ __align__(16) ushort sA[64 * ASTRIDE];
    __shared__ __align__(16) ushort sB[256 * BSTRIDE];
    const int t = threadIdx.x;
    const int mBase = blockIdx.x * 64;

    // Stage full A tile (64 rows x 256 k) as canonical bf16
    {
        int m = t >> 2, g = t & 3;
        int row = mBase + m;
        bool ok = row < N_NODES;
        if (isf32) {
            const float* src = (const float*)Tv + (size_t)row * 256;
            #pragma unroll
            for (int it = 0; it < 8; ++it) {
                int kk = (g + it * 4) * 8;
                float4 lo = ok ? *(const float4*)(src + kk)     : make_float4(0.f, 0.f, 0.f, 0.f);
                float4 hi = ok ? *(const float4*)(src + kk + 4) : make_float4(0.f, 0.f, 0.f, 0.f);
                uint4 val;
                val.x = (uint)f2bf(lo.x) | ((uint)f2bf(lo.y) << 16);
                val.y = (uint)f2bf(lo.z) | ((uint)f2bf(lo.w) << 16);
                val.z = (uint)f2bf(hi.x) | ((uint)f2bf(hi.y) << 16);
                val.w = (uint)f2bf(hi.z) | ((uint)f2bf(hi.w) << 16);
                *(uint4*)&sA[m * ASTRIDE + kk] = val;
            }
        } else {
            const ushort* src = (const ushort*)Tv + (size_t)row * 256;
            #pragma unroll
            for (int it = 0; it < 8; ++it) {
                int kk = (g + it * 4) * 8;
                uint4 val = ok ? *(const uint4*)(src + kk) : make_uint4(0u, 0u, 0u, 0u);
                *(uint4*)&sA[m * ASTRIDE + kk] = val;
            }
        }
    }

    const int lane = t & 63, wv = t >> 6;
    const int wm = (wv & 1) * 32, wn = (wv >> 1) * 32;
    const int fr = lane & 15;
    const int q  = lane >> 4;

    v4f acc[4][2][2] = {};

    for (int k0 = 0; k0 < 256; k0 += 32) {
        __syncthreads();    // 1st entry also fences the A staging
        {
            // stage B chunk: thread t owns n-row t, 32 k values (64 B)
            #pragma unroll
            for (int it = 0; it < 4; ++it)
                *(uint4*)&sB[t * BSTRIDE + it * 8] =
                    *(const uint4*)(WT + (size_t)t * 256 + k0 + it * 8);
        }
        __syncthreads();

        v8bf a0 = *(const v8bf*)&sA[(wm +      fr) * ASTRIDE + k0 + q * 8];
        v8bf a1 = *(const v8bf*)&sA[(wm + 16 + fr) * ASTRIDE + k0 + q * 8];
        #pragma unroll
        for (int nb = 0; nb < 4; ++nb) {
            v8bf b0 = *(const v8bf*)&sB[(nb * 64 + wn +      fr) * BSTRIDE + q * 8];
            v8bf b1 = *(const v8bf*)&sB[(nb * 64 + wn + 16 + fr) * BSTRIDE + q * 8];
            acc[nb][0][0] = __builtin_amdgcn_mfma_f32_16x16x32_bf16(a0, b0, acc[nb][0][0], 0, 0, 0);
            acc[nb][0][1] = __builtin_amdgcn_mfma_f32_16x16x32_bf16(a0, b1, acc[nb][0][1], 0, 0, 0);
            acc[nb][1][0] = __builtin_amdgcn_mfma_f32_16x16x32_bf16(a1, b0, acc[nb][1][0], 0, 0, 0);
            acc[nb][1][1] = __builtin_amdgcn_mfma_f32_16x16x32_bf16(a1, b1, acc[nb][1][1], 0, 0, 0);
        }
    }

    // Epilogue: D[row][col], row=(lane>>4)*4+r, col=lane&15; fused ReLU
    #pragma unroll
    for (int nb = 0; nb < 4; ++nb) {
        const int nBase = nb * 64;
        #pragma unroll
        for (int tm = 0; tm < 2; tm++) {
            #pragma unroll
            for (int tn = 0; tn < 2; tn++) {
                #pragma unroll
                for (int rr = 0; rr < 4; rr++) {
                    int grow = mBase + wm + tm * 16 + q * 4 + rr;
                    if (grow < N_NODES) {
                        int gcol = nBase + wn + tn * 16 + fr;
                        float v = fmaxf(acc[nb][tm][tn][rr], 0.f);
                        if (isf32) ((float*)Tv)[(size_t)grow * 256 + gcol] = v;
                        else       ((ushort*)Tv)[(size_t)grow * 256 + gcol] = f2bf(v);
                    }
                }
            }
        }
    }
}

// ---------------- workspace layout (bytes) — total ~5.53 MB ----------------
#define OFF_FLAG   ((size_t)0)          //       256
#define OFF_COUNTS ((size_t)256)        //   200,000
#define OFF_RPTR   ((size_t)200256)     //   200,000
#define OFF_CURSOR ((size_t)400256)     //   200,000
#define OFF_BSUMS  ((size_t)600256)     //     1,024
#define OFF_WT     ((size_t)601280)     //   131,072
#define OFF_ECOLS  ((size_t)732352)     // 3,200,000
#define OFF_EVALS  ((size_t)3932352)    // 1,600,000
// end = 5,532,352

extern "C" void kernel_launch(void* const* d_in, const int* in_sizes, int n_in,
                              void* d_out, int out_size, void* d_ws, size_t ws_size,
                              hipStream_t stream) {
    const void* X    = d_in[0];
    const void* W    = d_in[1];
    const void* VALS = d_in[2];
    const int*  ROWS = (const int*)d_in[3];
    const int*  COLS = (const int*)d_in[4];

    char* ws = (char*)d_ws;
    int*    flag   = (int*)(ws + OFF_FLAG);
    int*    counts = (int*)(ws + OFF_COUNTS);
    int*    rptr   = (int*)(ws + OFF_RPTR);
    int*    cursor = (int*)(ws + OFF_CURSOR);
    int*    bsums  = (int*)(ws + OFF_BSUMS);
    ushort* WT     = (ushort*)(ws + OFF_WT);
    int*    ecols  = (int*)(ws + OFF_ECOLS);
    ushort* evals  = (ushort*)(ws + OFF_EVALS);

    // zero flag + counts + row_ptr + cursor in one contiguous shot
    hipMemsetAsync(ws, 0, 600256, stream);

    k_detect<<<1, 256, 0, stream>>>((const ushort*)W, flag);
    k_transpose<<<256, 256, 0, stream>>>(W, WT, flag);
    k_hist<<<(N_EDGES + 255) / 256, 256, 0, stream>>>(ROWS, counts);
    k_scan1<<<196, 256, 0, stream>>>(counts, rptr, bsums, N_NODES);
    k_scan2<<<1, 256, 0, stream>>>(bsums, 196);
    k_scan3<<<196, 256, 0, stream>>>(rptr, counts, bsums, N_NODES);
    k_scatter<<<(N_EDGES + 255) / 256, 256, 0, stream>>>(ROWS, COLS, VALS, rptr, cursor,
                                                         ecols, evals, flag);
    k_spmm<<<N_NODES / 4, 256, 0, stream>>>(X, ecols, evals, rptr, counts, flag, d_out);
    k_gemm<<<(N_NODES + 63) / 64, 256, 0, stream>>>(d_out, WT, flag);
}